// Round 12
// baseline (440.196 us; speedup 1.0000x reference)
//
#include <hip/hip_runtime.h>
#include <type_traits>
#include <cstdint>
#include <cstddef>

#define N_FEAT 32
#define NBASIS 8
#define SPAN   16            // edges per half-wave slot
#define BSLOTS 8             // slots per 256-thread block
#define BEDGES (SPAN*BSLOTS) // contiguous edges staged per block

// ---------------------------------------------------------------------------
// Compile-time Clebsch-Gordan (real basis) table: constexpr port of the
// reference _cg / _u_real / _real_cg.  Values become inline literals in the
// unrolled MP kernels; zero entries are eliminated via `if constexpr`.
// ---------------------------------------------------------------------------
namespace cgc {

constexpr double dfact(int n){ double r=1.0; for(int i=2;i<=n;++i) r*=(double)i; return r; }

constexpr double dsqrt(double x){
  if(x<=0.0) return 0.0;
  double g = x>1.0 ? x : 1.0;
  for(int i=0;i<200;++i){ double ng = 0.5*(g + x/g); if(ng==g) break; g=ng; }
  return g;
}

constexpr double cg1(int j1,int m1,int j2,int m2,int j3,int m3){
  int adiff = j1-j2; if(adiff<0) adiff=-adiff;
  if(m1+m2!=m3 || j3<adiff || j3>j1+j2) return 0.0;
  double pre = dsqrt((double)(2*j3+1)*dfact(j1+j2-j3)*dfact(j1-j2+j3)*dfact(-j1+j2+j3)/dfact(j1+j2+j3+1));
  pre = pre*dsqrt(dfact(j3+m3)*dfact(j3-m3)*dfact(j1-m1)*dfact(j1+m1)*dfact(j2-m2)*dfact(j2+m2));
  double s=0.0;
  for(int k=0;k<=j1+j2+j3;++k){
    int d1=j1+j2-j3-k, d2=j1-m1-k, d3=j2+m2-k, d4=j3-j2+m1+k, d5=j3-j1-m2+k;
    if(d1<0||d2<0||d3<0||d4<0||d5<0) continue;
    double term = 1.0/(dfact(k)*dfact(d1)*dfact(d2)*dfact(d3)*dfact(d4)*dfact(d5));
    s += (k&1)? -term : term;
  }
  return pre*s;
}

struct Tab { float v[9][9][9]; };

constexpr Tab make(){
  Tab T{};
  int off[3]={0,1,4};
  double Ure[3][5][5]={}, Uim[3][5][5]={};
  const double s2 = dsqrt(0.5);
  for(int l=0;l<3;++l){
    for(int m=-l;m<=l;++m){
      int i=m+l;
      if(m==0){ Ure[l][i][l]=1.0; }
      else if(m>0){
        Ure[l][i][l+m] = ((m&1)? -1.0:1.0)*s2;
        Ure[l][i][l-m] = s2;
      } else {
        int am=-m;
        Uim[l][i][l+m] = s2;
        Uim[l][i][l-m] = -(((am&1)?-1.0:1.0))*s2;
      }
    }
  }
  for(int l1=0;l1<3;++l1) for(int l2=0;l2<3;++l2) for(int l3=0;l3<3;++l3){
    int lo = l1-l2; if(lo<0) lo=-lo;
    if(l3<lo || l3>l1+l2) continue;
    int d1=2*l1+1, d2=2*l2+1, d3=2*l3+1;
    double cg[5][5][5]={};
    for(int m1=-l1;m1<=l1;++m1) for(int m2=-l2;m2<=l2;++m2){
      int m3=m1+m2;
      if(m3>=-l3 && m3<=l3) cg[m1+l1][m2+l2][m3+l3] = cg1(l1,m1,l2,m2,l3,m3);
    }
    double t1re[5][5][5]={}, t1im[5][5][5]={};
    for(int a=0;a<d1;++a) for(int b=0;b<d2;++b) for(int k=0;k<d3;++k){
      double sre=0, sim=0;
      for(int c=0;c<d3;++c){
        double g=cg[a][b][c]; if(g==0.0) continue;
        sre += g*Ure[l3][k][c];
        sim -= g*Uim[l3][k][c];
      }
      t1re[a][b][k]=sre; t1im[a][b][k]=sim;
    }
    double t2re[5][5][5]={}, t2im[5][5][5]={};
    for(int a=0;a<d1;++a) for(int j=0;j<d2;++j) for(int k=0;k<d3;++k){
      double sre=0,sim=0;
      for(int b=0;b<d2;++b){
        double ur=Ure[l2][j][b], ui=Uim[l2][j][b];
        if(ur==0.0&&ui==0.0) continue;
        sre += ur*t1re[a][b][k]-ui*t1im[a][b][k];
        sim += ur*t1im[a][b][k]+ui*t1re[a][b][k];
      }
      t2re[a][j][k]=sre; t2im[a][j][k]=sim;
    }
    for(int i=0;i<d1;++i) for(int j=0;j<d2;++j) for(int k=0;k<d3;++k){
      double sre=0,sim=0;
      for(int a=0;a<d1;++a){
        double ur=Ure[l1][i][a], ui=Uim[l1][i][a];
        if(ur==0.0&&ui==0.0) continue;
        sre += ur*t2re[a][j][k]-ui*t2im[a][j][k];
        sim += ur*t2im[a][j][k]+ui*t2re[a][j][k];
      }
      T.v[off[l1]+i][off[l2]+j][off[l3]+k] = (float)(sre+sim);
    }
  }
  return T;
}

constexpr Tab T = make();

} // namespace cgc

template<int I, int N, typename F>
__device__ __forceinline__ void sfor(F&& f){
  if constexpr (I < N){
    f(std::integral_constant<int,I>{});
    sfor<I+1,N>(static_cast<F&&>(f));
  }
}

constexpr int LOFF[3] = {0,1,4};
constexpr float Y0C = 0.28209479177387814f;   // Y[0] constant, folded into Wreg

// Path sets (R19 = R18 + latency-matched pipeline DEPTHs).
// R18 counters: mp1 66% VALU-busy (34% stall), PS2 is DA=9 LLC-gather with
// only 3x~130cy cover (<600-900cy LLC latency) -> deepen: PS2 3->5,
// PS1a/b 3->4 (cheap in VGPR: +DA per extra buffer).
struct PS0 {   // layer 0
  static constexpr int NP=3;
  static constexpr int L[3][3]={{0,0,0},{0,1,1},{0,2,2}};
  static constexpr int ALO=0, AHI=1, OD=9, WOFF=0;
  static constexpr int MINW=4, DEPTH=8;
  static constexpr bool EMB=true;
};
struct PS1a {  // layer 1, l1 in {0,1}
  static constexpr int NP=9;
  static constexpr int L[9][3]={{0,0,0},{0,1,1},{0,2,2},
                                {1,0,1},{1,1,0},{1,1,1},{1,1,2},{1,2,1},{1,2,2}};
  static constexpr int ALO=0, AHI=4, OD=9, WOFF=0;
  static constexpr int MINW=3, DEPTH=4;
  static constexpr bool EMB=false;
};
struct PS1b {  // layer 1, l1 == 2 (W rows 9..14), atomically accumulates
  static constexpr int NP=6;
  static constexpr int L[6][3]={{2,0,2},{2,1,1},{2,1,2},{2,2,0},{2,2,1},{2,2,2}};
  static constexpr int ALO=4, AHI=9, OD=9, WOFF=9*NBASIS*N_FEAT;
  static constexpr int MINW=3, DEPTH=4;
  static constexpr bool EMB=false;
};
struct PS2 {   // layer 2
  static constexpr int NP=3;
  static constexpr int L[3][3]={{0,0,0},{1,1,0},{2,2,0}};
  static constexpr int ALO=0, AHI=9, OD=1, WOFF=0;
  static constexpr int MINW=3, DEPTH=5;
  static constexpr bool EMB=false;
};

// ---------------------------------------------------------------------------
// init: fuses {cnt zero, node embedding, ymsg zero} (one launch; replaces
// the first hipMemsetAsync).  nN*32 threads; each thread zeroes its 9 ymsg
// words exclusively -> race-free.
// ---------------------------------------------------------------------------
__global__ void init_kernel(const float* __restrict__ embed, const int* __restrict__ Z,
                            float* __restrict__ xA, float* __restrict__ ymsg,
                            int* __restrict__ cnt, int nN){
  int i = blockIdx.x*256 + threadIdx.x;
  if(i >= nN*N_FEAT) return;
  int n = i>>5, f = i&31;
  if(f==0) cnt[n]=0;
  xA[(size_t)n*288 + f] = embed[Z[n]*N_FEAT + f];
  #pragma unroll
  for(int c=0;c<9;++c) ymsg[((size_t)n*9+c)*32 + f] = 0.f;
}

__global__ void count_kernel(const int* __restrict__ dst, int* __restrict__ cnt, int E){
  int e = blockIdx.x*256 + threadIdx.x;
  if(e<E) atomicAdd(&cnt[dst[e]], 1);
}

__global__ void __launch_bounds__(1024) scan_kernel(const int* __restrict__ cnt,
                                                    int* __restrict__ cursor, int n){
  __shared__ int part[1024];
  const int tid = threadIdx.x;
  const int chunk = (n + 1023) >> 10;
  const int s0 = tid*chunk;
  const int s1 = (s0+chunk < n) ? s0+chunk : n;
  int s=0;
  for(int i=s0;i<s1;++i) s += cnt[i];
  part[tid]=s; __syncthreads();
  for(int off=1; off<1024; off<<=1){
    int v = 0;
    if(tid>=off) v = part[tid-off];
    __syncthreads();
    part[tid] += v;
    __syncthreads();
  }
  int run = part[tid] - s;           // exclusive prefix
  for(int i=s0;i<s1;++i){
    int cv = cnt[i];
    cursor[i]=run;
    run += cv;
  }
}

// ---------------------------------------------------------------------------
// fill+geom fused: CSR slot via cursor atomic, geometry written directly to
// the CSR slot.  srcsP packs src|dst<<16; zsrc stores Z[src] (u8, <119) for
// PS0's L1-resident embed gather.  Record = 16 floats (rad[8] + Y[1..8]);
// Y[0] const folded into Wreg.  sin(n*theta) via Chebyshev off one __sincosf.
// ---------------------------------------------------------------------------
__global__ void fillgeom_kernel(const int* __restrict__ dst, const int* __restrict__ src,
                                const int* __restrict__ Z, const float* __restrict__ dr,
                                int* __restrict__ cursor, int* __restrict__ srcsP,
                                unsigned char* __restrict__ zsrc,
                                float* __restrict__ radY, int E){
  int e = blockIdx.x*256 + threadIdx.x;
  if(e>=E) return;
  const int d = dst[e], s = src[e];
  const int pos = atomicAdd(&cursor[d], 1);
  srcsP[pos] = s | (d<<16);
  zsrc[pos]  = (unsigned char)Z[s];

  float dx=dr[3*e], dy=dr[3*e+1], dz=dr[3*e+2];
  float r2 = fmaf(dx,dx,fmaf(dy,dy,fmaf(dz,dz,1e-12f)));
  float r = sqrtf(r2);
  float inv = 1.f/r;
  float ux=dx*inv, uy=dy*inv, uz=dz*inv;
  float t = r*(1.f/6.f);
  t = fminf(fmaxf(t,0.f), 1.f-1e-6f);
  float cut = 0.f;
  if (r < 6.f) cut = __expf(1.f - 1.f/(1.f - t*t));
  if (d==s) cut = 0.f;
  float base = 0.57735026918962576f * inv * cut;   // sqrt(2/RMAX)=sqrt(1/3)
  float* o = radY + (size_t)pos*16;
  const float pir = 0.52359877559829887f * r;      // pi*r/6
  float sT, cT;
  __sincosf(pir, &sT, &cT);
  const float twoc = 2.f*cT;
  float sp = 0.f, sc = sT;                         // sin(0), sin(theta)
  o[0] = base*sc;
  #pragma unroll
  for(int nb=2; nb<=8; ++nb){
    float sn = fmaf(twoc, sc, -sp);                // sin(n t)=2cos t sin((n-1)t)-sin((n-2)t)
    o[nb-1] = base*sn;
    sp = sc; sc = sn;
  }
  o[8]  = 0.4886025119029199f*uy;                  // Y[1..8] (Y[0] const folded)
  o[9]  = 0.4886025119029199f*uz;
  o[10] = 0.4886025119029199f*ux;
  o[11] = 1.0925484305920792f*ux*uy;
  o[12] = 1.0925484305920792f*uy*uz;
  o[13] = 0.31539156525252005f*(3.f*uz*uz-1.f);
  o[14] = 1.0925484305920792f*ux*uz;
  o[15] = 0.5462742152960396f*(ux*ux-uy*uy);
}

// ---------------------------------------------------------------------------
// Message passing, EDGE-MAJOR, fully-unrolled slot loop (R10/R14/R15 lineage).
// mp_phase = everything after staging (Wreg load, pipeline, flush).
// PS0 gathers from the L1-resident embed table via staged u8 Z (EMB=true).
// ---------------------------------------------------------------------------
template<class PS>
__device__ __forceinline__ void mp_phase(
    int k0, int nE, const float* sRad, const int* sS, const unsigned char* sZb,
    const float* __restrict__ x_in, const float* __restrict__ emb,
    const float* __restrict__ W, float* __restrict__ ymsg, int f)
{
  constexpr int NP = PS::NP;
  constexpr int ALO = PS::ALO, AHI = PS::AHI, DA = AHI-ALO;
  constexpr int OD = PS::OD;
  constexpr int DEPTH = PS::DEPTH, NBUF = DEPTH+1;

  // path weights resident in VGPRs: lane f holds W[p][q][f].
  // l2==0 paths get Y0 pre-multiplied (Y[0] is a constant).
  float Wreg[NP][NBASIS];
  sfor<0,NP>([&](auto P){
    constexpr int p = P.value;
    constexpr bool fold = (PS::L[p][1]==0);
    sfor<0,NBASIS>([&](auto Q){
      float v = W[PS::WOFF + (p*NBASIS+Q.value)*N_FEAT + f];
      if constexpr (fold) v *= Y0C;
      Wreg[p][Q.value] = v;
    });
  });

  float msg[OD];
  sfor<0,OD>([&](auto C){ msg[C.value]=0.f; });

  auto gather = [&](float (&dst)[DA], int k){
    if constexpr (PS::EMB){
      const int zs = sZb[k];
      dst[0] = emb[zs*N_FEAT + f];       // 15KB table: L1-resident
    } else {
      const int s = sS[k] & 0xFFFF;
      const float* xb = x_in + (size_t)s*288 + ALO*N_FEAT + f;
      sfor<0,DA>([&](auto A){ dst[A.value] = xb[A.value*N_FEAT]; });
    }
  };

  auto compute = [&](const float (&xs)[DA], int k){
    const float* rp = sRad + k*16;
    const float4 q0 = *(const float4*)(rp);
    const float4 q1 = *(const float4*)(rp+4);
    const float4 q2 = *(const float4*)(rp+8);
    const float4 q3 = *(const float4*)(rp+12);
    const float rad[8] = {q0.x,q0.y,q0.z,q0.w,q1.x,q1.y,q1.z,q1.w};
    const float Yv[8]  = {q2.x,q2.y,q2.z,q2.w,q3.x,q3.y,q3.z,q3.w}; // Y[1..8]
    sfor<0,NP>([&](auto P){
      constexpr int p  = P.value;
      constexpr int l1 = PS::L[p][0], l2 = PS::L[p][1], l3 = PS::L[p][2];
      constexpr int o1 = LOFF[l1], o2 = LOFF[l2], o3 = LOFF[l3];
      float w = 0.f;
      sfor<0,NBASIS>([&](auto Q){ w = fmaf(rad[Q.value], Wreg[p][Q.value], w); });
      sfor<0,2*l2+1>([&](auto B){
        constexpr int b = B.value;
        float yw;
        if constexpr (l2==0) yw = w;            // Y0 folded into Wreg
        else                 yw = Yv[o2+b-1]*w; // Yv holds Y[1..8]
        sfor<0,2*l1+1>([&](auto A){
          constexpr int a = A.value;
          sfor<0,2*l3+1>([&](auto C){
            constexpr int c = C.value;
            constexpr float cgv = cgc::T.v[o1+a][o2+b][o3+c];
            if constexpr (cgv > 1e-7f || cgv < -1e-7f){
              msg[o3+c] = fmaf(cgv*xs[o1+a-ALO], yw, msg[o3+c]);
            }
          });
        });
      });
    });
  };

  auto flush = [&](int d){
    float* yb = ymsg + ((size_t)d*OD)*N_FEAT + f;
    sfor<0,OD>([&](auto C){
      atomicAdd(yb + C.value*N_FEAT, msg[C.value]);
      msg[C.value] = 0.f;
    });
  };

  if (k0 + SPAN <= nE){
    // -------- main path: exact SPAN edges, full unroll, register pipeline --
    float buf[NBUF][DA];
    sfor<0,DEPTH>([&](auto J){ gather(buf[J.value], k0 + J.value); });
    int vcur = sS[k0];
    sfor<0,SPAN>([&](auto I){
      constexpr int i = I.value;
      int vnext;
      if constexpr (i+1 < SPAN) vnext = sS[k0+i+1]; else vnext = -1;
      if constexpr (i+DEPTH < SPAN) gather(buf[(i+DEPTH)%NBUF], k0+i+DEPTH);
      compute(buf[i%NBUF], k0+i);
      if (i == SPAN-1 || (vnext>>16) != (vcur>>16)) flush(vcur>>16);
      vcur = vnext;
    });
  } else {
    // -------- tail fallback (partial block): simple 1-deep sequential ------
    const int k1 = (k0+SPAN < nE) ? k0+SPAN : nE;
    for (int k=k0; k<k1; ++k){
      float xs[DA];
      gather(xs, k);
      compute(xs, k);
      const int dc = sS[k]>>16;
      const int dn = (k+1 < k1) ? (sS[k+1]>>16) : -1;
      if (dn != dc) flush(dc);
    }
  }
}

// cooperative stage helper: radY burst + packed src/dst (+ optional u8 Z)
template<bool EMB>
__device__ __forceinline__ int mp_stage(
    int bid, float* sRad, int* sS, unsigned char* sZb,
    const int* __restrict__ srcsP, const unsigned char* __restrict__ zsrc,
    const float* __restrict__ radY, int E)
{
  const int tid  = threadIdx.x;
  const int base = bid * BEDGES;
  const int nE   = (base + BEDGES <= E) ? BEDGES : (E - base);
  {
    const float4* g4 = (const float4*)(radY + (size_t)base*16);
    float4* s4 = (float4*)sRad;
    const int n4 = nE*4;                    // nE*16/4
    for (int i=tid; i<n4; i+=256) s4[i] = g4[i];
    for (int i=tid; i<nE;  i+=256) sS[i] = srcsP[base+i];
    if constexpr (EMB){
      for (int i=tid; i<nE; i+=256) sZb[i] = zsrc[base+i];
    }
  }
  __syncthreads();
  return nE;
}

template<class PS>
__global__ void __launch_bounds__(256, PS::MINW) mp_kernel(
    const int* __restrict__ srcsP, const unsigned char* __restrict__ zsrc,
    const float* __restrict__ radY, const float* __restrict__ x_in,
    const float* __restrict__ emb, const float* __restrict__ W,
    float* __restrict__ ymsg, int E)
{
  __shared__ float sRad[BEDGES*16];
  __shared__ int   sS[BEDGES];
  __shared__ unsigned char sZb[BEDGES];
  const int nE = mp_stage<PS::EMB>(blockIdx.x, sRad, sS, sZb, srcsP, zsrc, radY, E);
  const int f  = threadIdx.x & 31;
  const int k0 = (threadIdx.x>>5)*SPAN;
  if (k0 >= nE) return;
  mp_phase<PS>(k0, nE, sRad, sS, sZb, x_in, emb, W, ymsg, f);
}

// layer-1 fused dispatch (R15 grid split, proven 154us): first gMP blocks run
// PS1a, next gMP run PS1b.  Separate register-allocation paths; atomic
// accumulation makes the interleaved execution order safe.
__global__ void __launch_bounds__(256, 3) mp1_kernel(
    const int* __restrict__ srcsP, const float* __restrict__ radY,
    const float* __restrict__ x_in, const float* __restrict__ W,
    float* __restrict__ ymsg, int E, int gMP)
{
  __shared__ float sRad[BEDGES*16];
  __shared__ int   sS[BEDGES];
  const int b = blockIdx.x;
  if (b < gMP){
    const int nE = mp_stage<false>(b, sRad, sS, nullptr, srcsP, nullptr, radY, E);
    const int f  = threadIdx.x & 31;
    const int k0 = (threadIdx.x>>5)*SPAN;
    if (k0 >= nE) return;
    mp_phase<PS1a>(k0, nE, sRad, sS, nullptr, x_in, nullptr, W, ymsg, f);
  } else {
    const int nE = mp_stage<false>(b-gMP, sRad, sS, nullptr, srcsP, nullptr, radY, E);
    const int f  = threadIdx.x & 31;
    const int k0 = (threadIdx.x>>5)*SPAN;
    if (k0 >= nE) return;
    mp_phase<PS1b>(k0, nE, sRad, sS, nullptr, x_in, nullptr, W, ymsg, f);
  }
}

// ---------------------------------------------------------------------------
// Node update for iterations 0/1.  ZERO=true (iteration 0) additionally
// re-zeroes ymsg in place (race-free: each thread zeroes exactly the words
// it read) and zeroes ymsg2 for the final layer -> no hipMemsetAsync at all.
// ---------------------------------------------------------------------------
template<int DX, bool ZERO>
__global__ void __launch_bounds__(256) nodeA_kernel(
    const float* __restrict__ xin, float* __restrict__ ymsg,
    float* __restrict__ ymsg2,
    const float* __restrict__ K1, const float* __restrict__ b1,
    const float* __restrict__ K2, const float* __restrict__ b2,
    float* __restrict__ xout, int nN)
{
  __shared__ float sK1[1024], sK2[1024], sb1[32], sb2[32];
  __shared__ float tb[8][9][32];
  const int tid = threadIdx.x;
  for(int i=tid;i<1024;i+=256){ sK1[i]=K1[i]; sK2[i]=K2[i]; }
  if(tid<32){ sb1[tid]=b1[tid]; sb2[tid]=b2[tid]; }
  __syncthreads();
  const int h = tid>>5, f = tid&31;
  const int n = blockIdx.x*8 + h;
  const bool valid = n < nN;
  const int nc = valid ? n : 0;
  float xi[9];
  #pragma unroll
  for(int c=0;c<9;++c){
    float t = ymsg[((size_t)nc*9+c)*32+f];
    if (ZERO && valid) ymsg[((size_t)nc*9+c)*32+f] = 0.f;
    float x = 0.f;
    if (c<DX) x = xin[((size_t)nc*9+c)*32+f];
    xi[c]=x;
    tb[h][c][f] = t + x;
  }
  if (ZERO && valid) ymsg2[(size_t)nc*32+f] = 0.f;
  __syncthreads();
  float u[9];
  #pragma unroll
  for(int c=0;c<9;++c){
    float acc = (c==0) ? sb1[f] : 0.f;
    #pragma unroll
    for(int g=0;g<32;++g) acc = fmaf(tb[h][c][g], sK1[g*32+f], acc);
    u[c]=acc;
  }
  const float gate = 1.f/(1.f+expf(-u[0]));   // silu(s)=s*gate; others *gate
  __syncthreads();
  #pragma unroll
  for(int c=0;c<9;++c) tb[h][c][f] = u[c]*gate;
  __syncthreads();
  #pragma unroll
  for(int c=0;c<9;++c){
    float acc = (c==0) ? sb2[f] : 0.f;
    #pragma unroll
    for(int g=0;g<32;++g) acc = fmaf(tb[h][c][g], sK2[g*32+f], acc);
    if (valid) xout[((size_t)n*9+c)*32+f] = acc + ((c<DX) ? xi[c] : 0.f);
  }
}

// Final iteration node update: scalar channel only; writes d_out (nN,32)
__global__ void __launch_bounds__(256) nodeB_kernel(
    const float* __restrict__ xin, const float* __restrict__ msg0,
    const float* __restrict__ K1, const float* __restrict__ b1,
    const float* __restrict__ K2, const float* __restrict__ b2,
    float* __restrict__ out, int nN)
{
  __shared__ float sK1[1024], sK2[1024], sb1[32], sb2[32];
  __shared__ float tb[8][32];
  const int tid = threadIdx.x;
  for(int i=tid;i<1024;i+=256){ sK1[i]=K1[i]; sK2[i]=K2[i]; }
  if(tid<32){ sb1[tid]=b1[tid]; sb2[tid]=b2[tid]; }
  __syncthreads();
  const int h = tid>>5, f = tid&31;
  const int n = blockIdx.x*8 + h;
  const bool valid = n < nN;
  const int nc = valid ? n : 0;
  const float x0 = xin[(size_t)nc*288 + f];      // x[:, 0:1] scalar channel
  tb[h][f] = msg0[(size_t)nc*32+f] + x0;
  __syncthreads();
  float acc = sb1[f];
  #pragma unroll
  for(int g=0;g<32;++g) acc = fmaf(tb[h][g], sK1[g*32+f], acc);
  const float gate = 1.f/(1.f+expf(-acc));
  const float v = acc*gate;
  __syncthreads();
  tb[h][f] = v;
  __syncthreads();
  float acc2 = sb2[f];
  #pragma unroll
  for(int g=0;g<32;++g) acc2 = fmaf(tb[h][g], sK2[g*32+f], acc2);
  if (valid) out[(size_t)n*32+f] = x0 + acc2;
}

// ---------------------------------------------------------------------------
extern "C" void kernel_launch(void* const* d_in, const int* in_sizes, int n_in,
                              void* d_out, int out_size, void* d_ws, size_t ws_size,
                              hipStream_t stream) {
  const float* dr    = (const float*)d_in[0];
  const int*   Z     = (const int*)  d_in[1];
  const int*   nbr   = (const int*)  d_in[2];
  const float* embed = (const float*)d_in[3];
  const float* wmp0  = (const float*)d_in[4];
  const float* wmp1  = (const float*)d_in[5];
  const float* wmp2  = (const float*)d_in[6];
  const float* dk1   = (const float*)d_in[7];
  const float* db1   = (const float*)d_in[8];
  const float* dk2   = (const float*)d_in[9];
  const float* db2   = (const float*)d_in[10];
  const int nN = in_sizes[1];
  const int E  = in_sizes[2]/2;
  const int* idx_i = nbr;       // dst
  const int* idx_j = nbr + E;   // src

  // workspace carve-up (256B aligned)
  uintptr_t base = (uintptr_t)d_ws;
  auto alloc = [&](size_t bytes)->void*{
    uintptr_t p = (base + 255) & ~(uintptr_t)255;
    base = p + bytes;
    return (void*)p;
  };
  float* radY    = (float*)alloc((size_t)E*16*4);
  int*   cnt     = (int*)  alloc((size_t)nN*4);
  int*   cursor  = (int*)  alloc((size_t)nN*4);
  int*   srcsP   = (int*)  alloc((size_t)E*4);
  unsigned char* zsrc = (unsigned char*)alloc((size_t)E);
  float* xA      = (float*)alloc((size_t)nN*288*4);
  float* xB      = (float*)alloc((size_t)nN*288*4);
  float* ymsg    = (float*)alloc((size_t)nN*288*4);
  float* ymsg2   = (float*)alloc((size_t)nN*32*4);

  const int gE  = (E+255)/256;
  const int gI  = (nN*N_FEAT+255)/256;
  const int gND = (nN+7)/8;                       // 8 nodes (half-waves) per block
  const int gMP = (E + BEDGES - 1) / BEDGES;      // blocks own BEDGES contiguous edges

  // prologue: init fuses cnt-zero + embedding + ymsg-zero; fill+geom fused
  init_kernel    <<<gI, 256, 0, stream>>>(embed, Z, xA, ymsg, cnt, nN);
  count_kernel   <<<gE, 256, 0, stream>>>(idx_i, cnt, E);
  scan_kernel    <<<1, 1024, 0, stream>>>(cnt, cursor, nN);
  fillgeom_kernel<<<gE, 256, 0, stream>>>(idx_i, idx_j, Z, dr, cursor, srcsP, zsrc, radY, E);

  // iteration 0 (ymsg pre-zeroed by init; PS0 gathers embed directly)
  mp_kernel<PS0><<<gMP, 256, 0, stream>>>(srcsP, zsrc, radY, xA, embed, wmp0, ymsg, E);
  nodeA_kernel<1,true><<<gND, 256, 0, stream>>>(xA, ymsg, ymsg2, dk1, db1, dk2, db2, xB, nN);
  // iteration 1: PS1a+PS1b in ONE dispatch via grid split (ymsg re-zeroed
  // by nodeA<1,true> above)
  mp1_kernel<<<2*gMP, 256, 0, stream>>>(srcsP, radY, xB, wmp1, ymsg, E, gMP);
  nodeA_kernel<9,false><<<gND, 256, 0, stream>>>(xB, ymsg, ymsg2, dk1+1024, db1+32, dk2+1024, db2+32, xA, nN);
  // iteration 2 (scalar output into ymsg2, zeroed by nodeA<1,true>)
  mp_kernel<PS2><<<gMP, 256, 0, stream>>>(srcsP, zsrc, radY, xA, embed, wmp2, ymsg2, E);
  nodeB_kernel<<<gND, 256, 0, stream>>>(xA, ymsg2, dk1+2048, db1+64, dk2+2048, db2+64,
                                        (float*)d_out, nN);
}

// Round 13
// 399.446 us; speedup vs baseline: 1.1020x; 1.1020x over previous
//
#include <hip/hip_runtime.h>
#include <type_traits>
#include <cstdint>
#include <cstddef>

#define N_FEAT 32
#define NBASIS 8
#define SPAN   16            // edges per half-wave slot
#define BSLOTS 8             // slots per 256-thread block
#define BEDGES (SPAN*BSLOTS) // contiguous edges staged per block

// ---------------------------------------------------------------------------
// Compile-time Clebsch-Gordan (real basis) table: constexpr port of the
// reference _cg / _u_real / _real_cg.  Values become inline literals in the
// unrolled MP kernels; zero entries are eliminated via `if constexpr`.
// ---------------------------------------------------------------------------
namespace cgc {

constexpr double dfact(int n){ double r=1.0; for(int i=2;i<=n;++i) r*=(double)i; return r; }

constexpr double dsqrt(double x){
  if(x<=0.0) return 0.0;
  double g = x>1.0 ? x : 1.0;
  for(int i=0;i<200;++i){ double ng = 0.5*(g + x/g); if(ng==g) break; g=ng; }
  return g;
}

constexpr double cg1(int j1,int m1,int j2,int m2,int j3,int m3){
  int adiff = j1-j2; if(adiff<0) adiff=-adiff;
  if(m1+m2!=m3 || j3<adiff || j3>j1+j2) return 0.0;
  double pre = dsqrt((double)(2*j3+1)*dfact(j1+j2-j3)*dfact(j1-j2+j3)*dfact(-j1+j2+j3)/dfact(j1+j2+j3+1));
  pre = pre*dsqrt(dfact(j3+m3)*dfact(j3-m3)*dfact(j1-m1)*dfact(j1+m1)*dfact(j2-m2)*dfact(j2+m2));
  double s=0.0;
  for(int k=0;k<=j1+j2+j3;++k){
    int d1=j1+j2-j3-k, d2=j1-m1-k, d3=j2+m2-k, d4=j3-j2+m1+k, d5=j3-j1-m2+k;
    if(d1<0||d2<0||d3<0||d4<0||d5<0) continue;
    double term = 1.0/(dfact(k)*dfact(d1)*dfact(d2)*dfact(d3)*dfact(d4)*dfact(d5));
    s += (k&1)? -term : term;
  }
  return pre*s;
}

struct Tab { float v[9][9][9]; };

constexpr Tab make(){
  Tab T{};
  int off[3]={0,1,4};
  double Ure[3][5][5]={}, Uim[3][5][5]={};
  const double s2 = dsqrt(0.5);
  for(int l=0;l<3;++l){
    for(int m=-l;m<=l;++m){
      int i=m+l;
      if(m==0){ Ure[l][i][l]=1.0; }
      else if(m>0){
        Ure[l][i][l+m] = ((m&1)? -1.0:1.0)*s2;
        Ure[l][i][l-m] = s2;
      } else {
        int am=-m;
        Uim[l][i][l+m] = s2;
        Uim[l][i][l-m] = -(((am&1)?-1.0:1.0))*s2;
      }
    }
  }
  for(int l1=0;l1<3;++l1) for(int l2=0;l2<3;++l2) for(int l3=0;l3<3;++l3){
    int lo = l1-l2; if(lo<0) lo=-lo;
    if(l3<lo || l3>l1+l2) continue;
    int d1=2*l1+1, d2=2*l2+1, d3=2*l3+1;
    double cg[5][5][5]={};
    for(int m1=-l1;m1<=l1;++m1) for(int m2=-l2;m2<=l2;++m2){
      int m3=m1+m2;
      if(m3>=-l3 && m3<=l3) cg[m1+l1][m2+l2][m3+l3] = cg1(l1,m1,l2,m2,l3,m3);
    }
    double t1re[5][5][5]={}, t1im[5][5][5]={};
    for(int a=0;a<d1;++a) for(int b=0;b<d2;++b) for(int k=0;k<d3;++k){
      double sre=0, sim=0;
      for(int c=0;c<d3;++c){
        double g=cg[a][b][c]; if(g==0.0) continue;
        sre += g*Ure[l3][k][c];
        sim -= g*Uim[l3][k][c];
      }
      t1re[a][b][k]=sre; t1im[a][b][k]=sim;
    }
    double t2re[5][5][5]={}, t2im[5][5][5]={};
    for(int a=0;a<d1;++a) for(int j=0;j<d2;++j) for(int k=0;k<d3;++k){
      double sre=0,sim=0;
      for(int b=0;b<d2;++b){
        double ur=Ure[l2][j][b], ui=Uim[l2][j][b];
        if(ur==0.0&&ui==0.0) continue;
        sre += ur*t1re[a][b][k]-ui*t1im[a][b][k];
        sim += ur*t1im[a][b][k]+ui*t1re[a][b][k];
      }
      t2re[a][j][k]=sre; t2im[a][j][k]=sim;
    }
    for(int i=0;i<d1;++i) for(int j=0;j<d2;++j) for(int k=0;k<d3;++k){
      double sre=0,sim=0;
      for(int a=0;a<d1;++a){
        double ur=Ure[l1][i][a], ui=Uim[l1][i][a];
        if(ur==0.0&&ui==0.0) continue;
        sre += ur*t2re[a][j][k]-ui*t2im[a][j][k];
        sim += ur*t2im[a][j][k]+ui*t2re[a][j][k];
      }
      T.v[off[l1]+i][off[l2]+j][off[l3]+k] = (float)(sre+sim);
    }
  }
  return T;
}

constexpr Tab T = make();

} // namespace cgc

template<int I, int N, typename F>
__device__ __forceinline__ void sfor(F&& f){
  if constexpr (I < N){
    f(std::integral_constant<int,I>{});
    sfor<I+1,N>(static_cast<F&&>(f));
  }
}

constexpr int LOFF[3] = {0,1,4};
constexpr float Y0C = 0.28209479177387814f;   // Y[0] constant, folded into Wreg

// Path sets (R20 = R18 config + PS2 DEPTH=5 only).
// R19 post-mortem: mp1 DEPTH 3->4 REGRESSED (159->204us, +36MB HBM traffic:
// deeper pipelines inflate the outstanding-load working set and thrash
// L2/LLC; the per-block DEPTH-gather prologue also lengthens).  DEPTH=3 is
// latency-matched for PS1's ~440cy body.  PS2's 3->5 was ~neutral-to-
// positive by subtraction (total reg 39.5 ~= mp1's own 45) -> kept.
struct PS0 {   // layer 0
  static constexpr int NP=3;
  static constexpr int L[3][3]={{0,0,0},{0,1,1},{0,2,2}};
  static constexpr int ALO=0, AHI=1, OD=9, WOFF=0;
  static constexpr int MINW=4, DEPTH=8;
  static constexpr bool EMB=true;
};
struct PS1a {  // layer 1, l1 in {0,1}
  static constexpr int NP=9;
  static constexpr int L[9][3]={{0,0,0},{0,1,1},{0,2,2},
                                {1,0,1},{1,1,0},{1,1,1},{1,1,2},{1,2,1},{1,2,2}};
  static constexpr int ALO=0, AHI=4, OD=9, WOFF=0;
  static constexpr int MINW=3, DEPTH=3;
  static constexpr bool EMB=false;
};
struct PS1b {  // layer 1, l1 == 2 (W rows 9..14), atomically accumulates
  static constexpr int NP=6;
  static constexpr int L[6][3]={{2,0,2},{2,1,1},{2,1,2},{2,2,0},{2,2,1},{2,2,2}};
  static constexpr int ALO=4, AHI=9, OD=9, WOFF=9*NBASIS*N_FEAT;
  static constexpr int MINW=3, DEPTH=3;
  static constexpr bool EMB=false;
};
struct PS2 {   // layer 2
  static constexpr int NP=3;
  static constexpr int L[3][3]={{0,0,0},{1,1,0},{2,2,0}};
  static constexpr int ALO=0, AHI=9, OD=1, WOFF=0;
  static constexpr int MINW=3, DEPTH=5;
  static constexpr bool EMB=false;
};

// ---------------------------------------------------------------------------
// init: fuses {cnt zero, node embedding, ymsg zero} (one launch; replaces
// the first hipMemsetAsync).  nN*32 threads; each thread zeroes its 9 ymsg
// words exclusively -> race-free.
// ---------------------------------------------------------------------------
__global__ void init_kernel(const float* __restrict__ embed, const int* __restrict__ Z,
                            float* __restrict__ xA, float* __restrict__ ymsg,
                            int* __restrict__ cnt, int nN){
  int i = blockIdx.x*256 + threadIdx.x;
  if(i >= nN*N_FEAT) return;
  int n = i>>5, f = i&31;
  if(f==0) cnt[n]=0;
  xA[(size_t)n*288 + f] = embed[Z[n]*N_FEAT + f];
  #pragma unroll
  for(int c=0;c<9;++c) ymsg[((size_t)n*9+c)*32 + f] = 0.f;
}

__global__ void count_kernel(const int* __restrict__ dst, int* __restrict__ cnt, int E){
  int e = blockIdx.x*256 + threadIdx.x;
  if(e<E) atomicAdd(&cnt[dst[e]], 1);
}

__global__ void __launch_bounds__(1024) scan_kernel(const int* __restrict__ cnt,
                                                    int* __restrict__ cursor, int n){
  __shared__ int part[1024];
  const int tid = threadIdx.x;
  const int chunk = (n + 1023) >> 10;
  const int s0 = tid*chunk;
  const int s1 = (s0+chunk < n) ? s0+chunk : n;
  int s=0;
  for(int i=s0;i<s1;++i) s += cnt[i];
  part[tid]=s; __syncthreads();
  for(int off=1; off<1024; off<<=1){
    int v = 0;
    if(tid>=off) v = part[tid-off];
    __syncthreads();
    part[tid] += v;
    __syncthreads();
  }
  int run = part[tid] - s;           // exclusive prefix
  for(int i=s0;i<s1;++i){
    int cv = cnt[i];
    cursor[i]=run;
    run += cv;
  }
}

// ---------------------------------------------------------------------------
// fill+geom fused: CSR slot via cursor atomic, geometry written directly to
// the CSR slot.  srcsP packs src|dst<<16; zsrc stores Z[src] (u8, <119) for
// PS0's L1-resident embed gather.  Record = 16 floats (rad[8] + Y[1..8]);
// Y[0] const folded into Wreg.  sin(n*theta) via Chebyshev off one __sincosf.
// ---------------------------------------------------------------------------
__global__ void fillgeom_kernel(const int* __restrict__ dst, const int* __restrict__ src,
                                const int* __restrict__ Z, const float* __restrict__ dr,
                                int* __restrict__ cursor, int* __restrict__ srcsP,
                                unsigned char* __restrict__ zsrc,
                                float* __restrict__ radY, int E){
  int e = blockIdx.x*256 + threadIdx.x;
  if(e>=E) return;
  const int d = dst[e], s = src[e];
  const int pos = atomicAdd(&cursor[d], 1);
  srcsP[pos] = s | (d<<16);
  zsrc[pos]  = (unsigned char)Z[s];

  float dx=dr[3*e], dy=dr[3*e+1], dz=dr[3*e+2];
  float r2 = fmaf(dx,dx,fmaf(dy,dy,fmaf(dz,dz,1e-12f)));
  float r = sqrtf(r2);
  float inv = 1.f/r;
  float ux=dx*inv, uy=dy*inv, uz=dz*inv;
  float t = r*(1.f/6.f);
  t = fminf(fmaxf(t,0.f), 1.f-1e-6f);
  float cut = 0.f;
  if (r < 6.f) cut = __expf(1.f - 1.f/(1.f - t*t));
  if (d==s) cut = 0.f;
  float base = 0.57735026918962576f * inv * cut;   // sqrt(2/RMAX)=sqrt(1/3)
  float* o = radY + (size_t)pos*16;
  const float pir = 0.52359877559829887f * r;      // pi*r/6
  float sT, cT;
  __sincosf(pir, &sT, &cT);
  const float twoc = 2.f*cT;
  float sp = 0.f, sc = sT;                         // sin(0), sin(theta)
  o[0] = base*sc;
  #pragma unroll
  for(int nb=2; nb<=8; ++nb){
    float sn = fmaf(twoc, sc, -sp);                // sin(n t)=2cos t sin((n-1)t)-sin((n-2)t)
    o[nb-1] = base*sn;
    sp = sc; sc = sn;
  }
  o[8]  = 0.4886025119029199f*uy;                  // Y[1..8] (Y[0] const folded)
  o[9]  = 0.4886025119029199f*uz;
  o[10] = 0.4886025119029199f*ux;
  o[11] = 1.0925484305920792f*ux*uy;
  o[12] = 1.0925484305920792f*uy*uz;
  o[13] = 0.31539156525252005f*(3.f*uz*uz-1.f);
  o[14] = 1.0925484305920792f*ux*uz;
  o[15] = 0.5462742152960396f*(ux*ux-uy*uy);
}

// ---------------------------------------------------------------------------
// Message passing, EDGE-MAJOR, fully-unrolled slot loop (R10/R14/R15 lineage).
// mp_phase = everything after staging (Wreg load, pipeline, flush).
// PS0 gathers from the L1-resident embed table via staged u8 Z (EMB=true).
// ---------------------------------------------------------------------------
template<class PS>
__device__ __forceinline__ void mp_phase(
    int k0, int nE, const float* sRad, const int* sS, const unsigned char* sZb,
    const float* __restrict__ x_in, const float* __restrict__ emb,
    const float* __restrict__ W, float* __restrict__ ymsg, int f)
{
  constexpr int NP = PS::NP;
  constexpr int ALO = PS::ALO, AHI = PS::AHI, DA = AHI-ALO;
  constexpr int OD = PS::OD;
  constexpr int DEPTH = PS::DEPTH, NBUF = DEPTH+1;

  // path weights resident in VGPRs: lane f holds W[p][q][f].
  // l2==0 paths get Y0 pre-multiplied (Y[0] is a constant).
  float Wreg[NP][NBASIS];
  sfor<0,NP>([&](auto P){
    constexpr int p = P.value;
    constexpr bool fold = (PS::L[p][1]==0);
    sfor<0,NBASIS>([&](auto Q){
      float v = W[PS::WOFF + (p*NBASIS+Q.value)*N_FEAT + f];
      if constexpr (fold) v *= Y0C;
      Wreg[p][Q.value] = v;
    });
  });

  float msg[OD];
  sfor<0,OD>([&](auto C){ msg[C.value]=0.f; });

  auto gather = [&](float (&dst)[DA], int k){
    if constexpr (PS::EMB){
      const int zs = sZb[k];
      dst[0] = emb[zs*N_FEAT + f];       // 15KB table: L1-resident
    } else {
      const int s = sS[k] & 0xFFFF;
      const float* xb = x_in + (size_t)s*288 + ALO*N_FEAT + f;
      sfor<0,DA>([&](auto A){ dst[A.value] = xb[A.value*N_FEAT]; });
    }
  };

  auto compute = [&](const float (&xs)[DA], int k){
    const float* rp = sRad + k*16;
    const float4 q0 = *(const float4*)(rp);
    const float4 q1 = *(const float4*)(rp+4);
    const float4 q2 = *(const float4*)(rp+8);
    const float4 q3 = *(const float4*)(rp+12);
    const float rad[8] = {q0.x,q0.y,q0.z,q0.w,q1.x,q1.y,q1.z,q1.w};
    const float Yv[8]  = {q2.x,q2.y,q2.z,q2.w,q3.x,q3.y,q3.z,q3.w}; // Y[1..8]
    sfor<0,NP>([&](auto P){
      constexpr int p  = P.value;
      constexpr int l1 = PS::L[p][0], l2 = PS::L[p][1], l3 = PS::L[p][2];
      constexpr int o1 = LOFF[l1], o2 = LOFF[l2], o3 = LOFF[l3];
      float w = 0.f;
      sfor<0,NBASIS>([&](auto Q){ w = fmaf(rad[Q.value], Wreg[p][Q.value], w); });
      sfor<0,2*l2+1>([&](auto B){
        constexpr int b = B.value;
        float yw;
        if constexpr (l2==0) yw = w;            // Y0 folded into Wreg
        else                 yw = Yv[o2+b-1]*w; // Yv holds Y[1..8]
        sfor<0,2*l1+1>([&](auto A){
          constexpr int a = A.value;
          sfor<0,2*l3+1>([&](auto C){
            constexpr int c = C.value;
            constexpr float cgv = cgc::T.v[o1+a][o2+b][o3+c];
            if constexpr (cgv > 1e-7f || cgv < -1e-7f){
              msg[o3+c] = fmaf(cgv*xs[o1+a-ALO], yw, msg[o3+c]);
            }
          });
        });
      });
    });
  };

  auto flush = [&](int d){
    float* yb = ymsg + ((size_t)d*OD)*N_FEAT + f;
    sfor<0,OD>([&](auto C){
      atomicAdd(yb + C.value*N_FEAT, msg[C.value]);
      msg[C.value] = 0.f;
    });
  };

  if (k0 + SPAN <= nE){
    // -------- main path: exact SPAN edges, full unroll, register pipeline --
    float buf[NBUF][DA];
    sfor<0,DEPTH>([&](auto J){ gather(buf[J.value], k0 + J.value); });
    int vcur = sS[k0];
    sfor<0,SPAN>([&](auto I){
      constexpr int i = I.value;
      int vnext;
      if constexpr (i+1 < SPAN) vnext = sS[k0+i+1]; else vnext = -1;
      if constexpr (i+DEPTH < SPAN) gather(buf[(i+DEPTH)%NBUF], k0+i+DEPTH);
      compute(buf[i%NBUF], k0+i);
      if (i == SPAN-1 || (vnext>>16) != (vcur>>16)) flush(vcur>>16);
      vcur = vnext;
    });
  } else {
    // -------- tail fallback (partial block): simple 1-deep sequential ------
    const int k1 = (k0+SPAN < nE) ? k0+SPAN : nE;
    for (int k=k0; k<k1; ++k){
      float xs[DA];
      gather(xs, k);
      compute(xs, k);
      const int dc = sS[k]>>16;
      const int dn = (k+1 < k1) ? (sS[k+1]>>16) : -1;
      if (dn != dc) flush(dc);
    }
  }
}

// cooperative stage helper: radY burst + packed src/dst (+ optional u8 Z)
template<bool EMB>
__device__ __forceinline__ int mp_stage(
    int bid, float* sRad, int* sS, unsigned char* sZb,
    const int* __restrict__ srcsP, const unsigned char* __restrict__ zsrc,
    const float* __restrict__ radY, int E)
{
  const int tid  = threadIdx.x;
  const int base = bid * BEDGES;
  const int nE   = (base + BEDGES <= E) ? BEDGES : (E - base);
  {
    const float4* g4 = (const float4*)(radY + (size_t)base*16);
    float4* s4 = (float4*)sRad;
    const int n4 = nE*4;                    // nE*16/4
    for (int i=tid; i<n4; i+=256) s4[i] = g4[i];
    for (int i=tid; i<nE;  i+=256) sS[i] = srcsP[base+i];
    if constexpr (EMB){
      for (int i=tid; i<nE; i+=256) sZb[i] = zsrc[base+i];
    }
  }
  __syncthreads();
  return nE;
}

template<class PS>
__global__ void __launch_bounds__(256, PS::MINW) mp_kernel(
    const int* __restrict__ srcsP, const unsigned char* __restrict__ zsrc,
    const float* __restrict__ radY, const float* __restrict__ x_in,
    const float* __restrict__ emb, const float* __restrict__ W,
    float* __restrict__ ymsg, int E)
{
  __shared__ float sRad[BEDGES*16];
  __shared__ int   sS[BEDGES];
  __shared__ unsigned char sZb[BEDGES];
  const int nE = mp_stage<PS::EMB>(blockIdx.x, sRad, sS, sZb, srcsP, zsrc, radY, E);
  const int f  = threadIdx.x & 31;
  const int k0 = (threadIdx.x>>5)*SPAN;
  if (k0 >= nE) return;
  mp_phase<PS>(k0, nE, sRad, sS, sZb, x_in, emb, W, ymsg, f);
}

// layer-1 fused dispatch (R15 grid split, proven 154us): first gMP blocks run
// PS1a, next gMP run PS1b.  Separate register-allocation paths; atomic
// accumulation makes the interleaved execution order safe.
__global__ void __launch_bounds__(256, 3) mp1_kernel(
    const int* __restrict__ srcsP, const float* __restrict__ radY,
    const float* __restrict__ x_in, const float* __restrict__ W,
    float* __restrict__ ymsg, int E, int gMP)
{
  __shared__ float sRad[BEDGES*16];
  __shared__ int   sS[BEDGES];
  const int b = blockIdx.x;
  if (b < gMP){
    const int nE = mp_stage<false>(b, sRad, sS, nullptr, srcsP, nullptr, radY, E);
    const int f  = threadIdx.x & 31;
    const int k0 = (threadIdx.x>>5)*SPAN;
    if (k0 >= nE) return;
    mp_phase<PS1a>(k0, nE, sRad, sS, nullptr, x_in, nullptr, W, ymsg, f);
  } else {
    const int nE = mp_stage<false>(b-gMP, sRad, sS, nullptr, srcsP, nullptr, radY, E);
    const int f  = threadIdx.x & 31;
    const int k0 = (threadIdx.x>>5)*SPAN;
    if (k0 >= nE) return;
    mp_phase<PS1b>(k0, nE, sRad, sS, nullptr, x_in, nullptr, W, ymsg, f);
  }
}

// ---------------------------------------------------------------------------
// Node update for iterations 0/1.  ZERO=true (iteration 0) additionally
// re-zeroes ymsg in place (race-free: each thread zeroes exactly the words
// it read) and zeroes ymsg2 for the final layer -> no hipMemsetAsync at all.
// ---------------------------------------------------------------------------
template<int DX, bool ZERO>
__global__ void __launch_bounds__(256) nodeA_kernel(
    const float* __restrict__ xin, float* __restrict__ ymsg,
    float* __restrict__ ymsg2,
    const float* __restrict__ K1, const float* __restrict__ b1,
    const float* __restrict__ K2, const float* __restrict__ b2,
    float* __restrict__ xout, int nN)
{
  __shared__ float sK1[1024], sK2[1024], sb1[32], sb2[32];
  __shared__ float tb[8][9][32];
  const int tid = threadIdx.x;
  for(int i=tid;i<1024;i+=256){ sK1[i]=K1[i]; sK2[i]=K2[i]; }
  if(tid<32){ sb1[tid]=b1[tid]; sb2[tid]=b2[tid]; }
  __syncthreads();
  const int h = tid>>5, f = tid&31;
  const int n = blockIdx.x*8 + h;
  const bool valid = n < nN;
  const int nc = valid ? n : 0;
  float xi[9];
  #pragma unroll
  for(int c=0;c<9;++c){
    float t = ymsg[((size_t)nc*9+c)*32+f];
    if (ZERO && valid) ymsg[((size_t)nc*9+c)*32+f] = 0.f;
    float x = 0.f;
    if (c<DX) x = xin[((size_t)nc*9+c)*32+f];
    xi[c]=x;
    tb[h][c][f] = t + x;
  }
  if (ZERO && valid) ymsg2[(size_t)nc*32+f] = 0.f;
  __syncthreads();
  float u[9];
  #pragma unroll
  for(int c=0;c<9;++c){
    float acc = (c==0) ? sb1[f] : 0.f;
    #pragma unroll
    for(int g=0;g<32;++g) acc = fmaf(tb[h][c][g], sK1[g*32+f], acc);
    u[c]=acc;
  }
  const float gate = 1.f/(1.f+expf(-u[0]));   // silu(s)=s*gate; others *gate
  __syncthreads();
  #pragma unroll
  for(int c=0;c<9;++c) tb[h][c][f] = u[c]*gate;
  __syncthreads();
  #pragma unroll
  for(int c=0;c<9;++c){
    float acc = (c==0) ? sb2[f] : 0.f;
    #pragma unroll
    for(int g=0;g<32;++g) acc = fmaf(tb[h][c][g], sK2[g*32+f], acc);
    if (valid) xout[((size_t)n*9+c)*32+f] = acc + ((c<DX) ? xi[c] : 0.f);
  }
}

// Final iteration node update: scalar channel only; writes d_out (nN,32)
__global__ void __launch_bounds__(256) nodeB_kernel(
    const float* __restrict__ xin, const float* __restrict__ msg0,
    const float* __restrict__ K1, const float* __restrict__ b1,
    const float* __restrict__ K2, const float* __restrict__ b2,
    float* __restrict__ out, int nN)
{
  __shared__ float sK1[1024], sK2[1024], sb1[32], sb2[32];
  __shared__ float tb[8][32];
  const int tid = threadIdx.x;
  for(int i=tid;i<1024;i+=256){ sK1[i]=K1[i]; sK2[i]=K2[i]; }
  if(tid<32){ sb1[tid]=b1[tid]; sb2[tid]=b2[tid]; }
  __syncthreads();
  const int h = tid>>5, f = tid&31;
  const int n = blockIdx.x*8 + h;
  const bool valid = n < nN;
  const int nc = valid ? n : 0;
  const float x0 = xin[(size_t)nc*288 + f];      // x[:, 0:1] scalar channel
  tb[h][f] = msg0[(size_t)nc*32+f] + x0;
  __syncthreads();
  float acc = sb1[f];
  #pragma unroll
  for(int g=0;g<32;++g) acc = fmaf(tb[h][g], sK1[g*32+f], acc);
  const float gate = 1.f/(1.f+expf(-acc));
  const float v = acc*gate;
  __syncthreads();
  tb[h][f] = v;
  __syncthreads();
  float acc2 = sb2[f];
  #pragma unroll
  for(int g=0;g<32;++g) acc2 = fmaf(tb[h][g], sK2[g*32+f], acc2);
  if (valid) out[(size_t)n*32+f] = x0 + acc2;
}

// ---------------------------------------------------------------------------
extern "C" void kernel_launch(void* const* d_in, const int* in_sizes, int n_in,
                              void* d_out, int out_size, void* d_ws, size_t ws_size,
                              hipStream_t stream) {
  const float* dr    = (const float*)d_in[0];
  const int*   Z     = (const int*)  d_in[1];
  const int*   nbr   = (const int*)  d_in[2];
  const float* embed = (const float*)d_in[3];
  const float* wmp0  = (const float*)d_in[4];
  const float* wmp1  = (const float*)d_in[5];
  const float* wmp2  = (const float*)d_in[6];
  const float* dk1   = (const float*)d_in[7];
  const float* db1   = (const float*)d_in[8];
  const float* dk2   = (const float*)d_in[9];
  const float* db2   = (const float*)d_in[10];
  const int nN = in_sizes[1];
  const int E  = in_sizes[2]/2;
  const int* idx_i = nbr;       // dst
  const int* idx_j = nbr + E;   // src

  // workspace carve-up (256B aligned)
  uintptr_t base = (uintptr_t)d_ws;
  auto alloc = [&](size_t bytes)->void*{
    uintptr_t p = (base + 255) & ~(uintptr_t)255;
    base = p + bytes;
    return (void*)p;
  };
  float* radY    = (float*)alloc((size_t)E*16*4);
  int*   cnt     = (int*)  alloc((size_t)nN*4);
  int*   cursor  = (int*)  alloc((size_t)nN*4);
  int*   srcsP   = (int*)  alloc((size_t)E*4);
  unsigned char* zsrc = (unsigned char*)alloc((size_t)E);
  float* xA      = (float*)alloc((size_t)nN*288*4);
  float* xB      = (float*)alloc((size_t)nN*288*4);
  float* ymsg    = (float*)alloc((size_t)nN*288*4);
  float* ymsg2   = (float*)alloc((size_t)nN*32*4);

  const int gE  = (E+255)/256;
  const int gI  = (nN*N_FEAT+255)/256;
  const int gND = (nN+7)/8;                       // 8 nodes (half-waves) per block
  const int gMP = (E + BEDGES - 1) / BEDGES;      // blocks own BEDGES contiguous edges

  // prologue: init fuses cnt-zero + embedding + ymsg-zero; fill+geom fused
  init_kernel    <<<gI, 256, 0, stream>>>(embed, Z, xA, ymsg, cnt, nN);
  count_kernel   <<<gE, 256, 0, stream>>>(idx_i, cnt, E);
  scan_kernel    <<<1, 1024, 0, stream>>>(cnt, cursor, nN);
  fillgeom_kernel<<<gE, 256, 0, stream>>>(idx_i, idx_j, Z, dr, cursor, srcsP, zsrc, radY, E);

  // iteration 0 (ymsg pre-zeroed by init; PS0 gathers embed directly)
  mp_kernel<PS0><<<gMP, 256, 0, stream>>>(srcsP, zsrc, radY, xA, embed, wmp0, ymsg, E);
  nodeA_kernel<1,true><<<gND, 256, 0, stream>>>(xA, ymsg, ymsg2, dk1, db1, dk2, db2, xB, nN);
  // iteration 1: PS1a+PS1b in ONE dispatch via grid split (ymsg re-zeroed
  // by nodeA<1,true> above)
  mp1_kernel<<<2*gMP, 256, 0, stream>>>(srcsP, radY, xB, wmp1, ymsg, E, gMP);
  nodeA_kernel<9,false><<<gND, 256, 0, stream>>>(xB, ymsg, ymsg2, dk1+1024, db1+32, dk2+1024, db2+32, xA, nN);
  // iteration 2 (scalar output into ymsg2, zeroed by nodeA<1,true>)
  mp_kernel<PS2><<<gMP, 256, 0, stream>>>(srcsP, zsrc, radY, xA, embed, wmp2, ymsg2, E);
  nodeB_kernel<<<gND, 256, 0, stream>>>(xA, ymsg2, dk1+2048, db1+64, dk2+2048, db2+64,
                                        (float*)d_out, nN);
}

// Round 14
// 394.487 us; speedup vs baseline: 1.1159x; 1.0126x over previous
//
#include <hip/hip_runtime.h>
#include <type_traits>
#include <cstdint>
#include <cstddef>

#define N_FEAT 32
#define NBASIS 8
#define SPAN   16            // edges per half-wave slot
#define BSLOTS 8             // slots per 256-thread block
#define BEDGES (SPAN*BSLOTS) // contiguous edges staged per block

// ---------------------------------------------------------------------------
// Compile-time Clebsch-Gordan (real basis) table: constexpr port of the
// reference _cg / _u_real / _real_cg.  Values become inline literals in the
// unrolled MP kernels; zero entries are eliminated via `if constexpr`.
// ---------------------------------------------------------------------------
namespace cgc {

constexpr double dfact(int n){ double r=1.0; for(int i=2;i<=n;++i) r*=(double)i; return r; }

constexpr double dsqrt(double x){
  if(x<=0.0) return 0.0;
  double g = x>1.0 ? x : 1.0;
  for(int i=0;i<200;++i){ double ng = 0.5*(g + x/g); if(ng==g) break; g=ng; }
  return g;
}

constexpr double cg1(int j1,int m1,int j2,int m2,int j3,int m3){
  int adiff = j1-j2; if(adiff<0) adiff=-adiff;
  if(m1+m2!=m3 || j3<adiff || j3>j1+j2) return 0.0;
  double pre = dsqrt((double)(2*j3+1)*dfact(j1+j2-j3)*dfact(j1-j2+j3)*dfact(-j1+j2+j3)/dfact(j1+j2+j3+1));
  pre = pre*dsqrt(dfact(j3+m3)*dfact(j3-m3)*dfact(j1-m1)*dfact(j1+m1)*dfact(j2-m2)*dfact(j2+m2));
  double s=0.0;
  for(int k=0;k<=j1+j2+j3;++k){
    int d1=j1+j2-j3-k, d2=j1-m1-k, d3=j2+m2-k, d4=j3-j2+m1+k, d5=j3-j1-m2+k;
    if(d1<0||d2<0||d3<0||d4<0||d5<0) continue;
    double term = 1.0/(dfact(k)*dfact(d1)*dfact(d2)*dfact(d3)*dfact(d4)*dfact(d5));
    s += (k&1)? -term : term;
  }
  return pre*s;
}

struct Tab { float v[9][9][9]; };

constexpr Tab make(){
  Tab T{};
  int off[3]={0,1,4};
  double Ure[3][5][5]={}, Uim[3][5][5]={};
  const double s2 = dsqrt(0.5);
  for(int l=0;l<3;++l){
    for(int m=-l;m<=l;++m){
      int i=m+l;
      if(m==0){ Ure[l][i][l]=1.0; }
      else if(m>0){
        Ure[l][i][l+m] = ((m&1)? -1.0:1.0)*s2;
        Ure[l][i][l-m] = s2;
      } else {
        int am=-m;
        Uim[l][i][l+m] = s2;
        Uim[l][i][l-m] = -(((am&1)?-1.0:1.0))*s2;
      }
    }
  }
  for(int l1=0;l1<3;++l1) for(int l2=0;l2<3;++l2) for(int l3=0;l3<3;++l3){
    int lo = l1-l2; if(lo<0) lo=-lo;
    if(l3<lo || l3>l1+l2) continue;
    int d1=2*l1+1, d2=2*l2+1, d3=2*l3+1;
    double cg[5][5][5]={};
    for(int m1=-l1;m1<=l1;++m1) for(int m2=-l2;m2<=l2;++m2){
      int m3=m1+m2;
      if(m3>=-l3 && m3<=l3) cg[m1+l1][m2+l2][m3+l3] = cg1(l1,m1,l2,m2,l3,m3);
    }
    double t1re[5][5][5]={}, t1im[5][5][5]={};
    for(int a=0;a<d1;++a) for(int b=0;b<d2;++b) for(int k=0;k<d3;++k){
      double sre=0, sim=0;
      for(int c=0;c<d3;++c){
        double g=cg[a][b][c]; if(g==0.0) continue;
        sre += g*Ure[l3][k][c];
        sim -= g*Uim[l3][k][c];
      }
      t1re[a][b][k]=sre; t1im[a][b][k]=sim;
    }
    double t2re[5][5][5]={}, t2im[5][5][5]={};
    for(int a=0;a<d1;++a) for(int j=0;j<d2;++j) for(int k=0;k<d3;++k){
      double sre=0,sim=0;
      for(int b=0;b<d2;++b){
        double ur=Ure[l2][j][b], ui=Uim[l2][j][b];
        if(ur==0.0&&ui==0.0) continue;
        sre += ur*t1re[a][b][k]-ui*t1im[a][b][k];
        sim += ur*t1im[a][b][k]+ui*t1re[a][b][k];
      }
      t2re[a][j][k]=sre; t2im[a][j][k]=sim;
    }
    for(int i=0;i<d1;++i) for(int j=0;j<d2;++j) for(int k=0;k<d3;++k){
      double sre=0,sim=0;
      for(int a=0;a<d1;++a){
        double ur=Ure[l1][i][a], ui=Uim[l1][i][a];
        if(ur==0.0&&ui==0.0) continue;
        sre += ur*t2re[a][j][k]-ui*t2im[a][j][k];
        sim += ur*t2im[a][j][k]+ui*t2re[a][j][k];
      }
      T.v[off[l1]+i][off[l2]+j][off[l3]+k] = (float)(sre+sim);
    }
  }
  return T;
}

constexpr Tab T = make();

} // namespace cgc

template<int I, int N, typename F>
__device__ __forceinline__ void sfor(F&& f){
  if constexpr (I < N){
    f(std::integral_constant<int,I>{});
    sfor<I+1,N>(static_cast<F&&>(f));
  }
}

constexpr int LOFF[3] = {0,1,4};
constexpr float Y0C = 0.28209479177387814f;   // Y[0] constant, folded into Wreg

// Path sets (R21 = R20 + dead-edge compaction).  Depth lever CLOSED:
// PS0=8(EMB), PS1=3, PS2=5 all measured (R19: deeper mp1 thrashes L2).
// ~2.9% of edges have r>=6 (cut=0 => rad=0 => zero contribution); they are
// now dropped at CSR build, shrinking every mp pass proportionally.
struct PS0 {   // layer 0
  static constexpr int NP=3;
  static constexpr int L[3][3]={{0,0,0},{0,1,1},{0,2,2}};
  static constexpr int ALO=0, AHI=1, OD=9, WOFF=0;
  static constexpr int MINW=4, DEPTH=8;
  static constexpr bool EMB=true;
};
struct PS1a {  // layer 1, l1 in {0,1}
  static constexpr int NP=9;
  static constexpr int L[9][3]={{0,0,0},{0,1,1},{0,2,2},
                                {1,0,1},{1,1,0},{1,1,1},{1,1,2},{1,2,1},{1,2,2}};
  static constexpr int ALO=0, AHI=4, OD=9, WOFF=0;
  static constexpr int MINW=3, DEPTH=3;
  static constexpr bool EMB=false;
};
struct PS1b {  // layer 1, l1 == 2 (W rows 9..14), atomically accumulates
  static constexpr int NP=6;
  static constexpr int L[6][3]={{2,0,2},{2,1,1},{2,1,2},{2,2,0},{2,2,1},{2,2,2}};
  static constexpr int ALO=4, AHI=9, OD=9, WOFF=9*NBASIS*N_FEAT;
  static constexpr int MINW=3, DEPTH=3;
  static constexpr bool EMB=false;
};
struct PS2 {   // layer 2
  static constexpr int NP=3;
  static constexpr int L[3][3]={{0,0,0},{1,1,0},{2,2,0}};
  static constexpr int ALO=0, AHI=9, OD=1, WOFF=0;
  static constexpr int MINW=3, DEPTH=5;
  static constexpr bool EMB=false;
};

// live predicate: MUST be the bit-identical float sequence in count_kernel
// and fillgeom_kernel so both agree on every edge.
__device__ __forceinline__ bool edge_live(const float* __restrict__ dr, int e,
                                          int d, int s, float& r_out){
  float dx=dr[3*e], dy=dr[3*e+1], dz=dr[3*e+2];
  float r2 = fmaf(dx,dx,fmaf(dy,dy,fmaf(dz,dz,1e-12f)));
  float r = sqrtf(r2);
  r_out = r;
  return (r < 6.f) && (d != s);
}

// ---------------------------------------------------------------------------
// init: fuses {cnt zero, node embedding, ymsg zero} (one launch).
// ---------------------------------------------------------------------------
__global__ void init_kernel(const float* __restrict__ embed, const int* __restrict__ Z,
                            float* __restrict__ xA, float* __restrict__ ymsg,
                            int* __restrict__ cnt, int nN){
  int i = blockIdx.x*256 + threadIdx.x;
  if(i >= nN*N_FEAT) return;
  int n = i>>5, f = i&31;
  if(f==0) cnt[n]=0;
  xA[(size_t)n*288 + f] = embed[Z[n]*N_FEAT + f];
  #pragma unroll
  for(int c=0;c<9;++c) ymsg[((size_t)n*9+c)*32 + f] = 0.f;
}

// count LIVE edges only (dead edges contribute exactly zero downstream)
__global__ void count_kernel(const int* __restrict__ dst, const int* __restrict__ src,
                             const float* __restrict__ dr, int* __restrict__ cnt, int E){
  int e = blockIdx.x*256 + threadIdx.x;
  if(e>=E) return;
  const int d = dst[e], s = src[e];
  float r;
  if (edge_live(dr, e, d, s, r)) atomicAdd(&cnt[d], 1);
}

__global__ void __launch_bounds__(1024) scan_kernel(const int* __restrict__ cnt,
                                                    int* __restrict__ cursor,
                                                    int* __restrict__ Elive, int n){
  __shared__ int part[1024];
  const int tid = threadIdx.x;
  const int chunk = (n + 1023) >> 10;
  const int s0 = tid*chunk;
  const int s1 = (s0+chunk < n) ? s0+chunk : n;
  int s=0;
  for(int i=s0;i<s1;++i) s += cnt[i];
  part[tid]=s; __syncthreads();
  for(int off=1; off<1024; off<<=1){
    int v = 0;
    if(tid>=off) v = part[tid-off];
    __syncthreads();
    part[tid] += v;
    __syncthreads();
  }
  int run = part[tid] - s;           // exclusive prefix
  for(int i=s0;i<s1;++i){
    int cv = cnt[i];
    cursor[i]=run;
    run += cv;
  }
  if(tid==1023) Elive[0] = run;      // total live edges
}

// ---------------------------------------------------------------------------
// fill+geom fused: LIVE edges only get a CSR slot + geometry record.
// srcsP packs src|dst<<16; zsrc stores Z[src] (u8) for PS0's embed gather.
// Record = 16 floats (rad[8] + Y[1..8]); Y[0] const folded into Wreg.
// ---------------------------------------------------------------------------
__global__ void fillgeom_kernel(const int* __restrict__ dst, const int* __restrict__ src,
                                const int* __restrict__ Z, const float* __restrict__ dr,
                                int* __restrict__ cursor, int* __restrict__ srcsP,
                                unsigned char* __restrict__ zsrc,
                                float* __restrict__ radY, int E){
  int e = blockIdx.x*256 + threadIdx.x;
  if(e>=E) return;
  const int d = dst[e], s = src[e];
  float r;
  if (!edge_live(dr, e, d, s, r)) return;
  const int pos = atomicAdd(&cursor[d], 1);
  srcsP[pos] = s | (d<<16);
  zsrc[pos]  = (unsigned char)Z[s];

  float dx=dr[3*e], dy=dr[3*e+1], dz=dr[3*e+2];
  float inv = 1.f/r;
  float ux=dx*inv, uy=dy*inv, uz=dz*inv;
  float t = r*(1.f/6.f);
  t = fminf(fmaxf(t,0.f), 1.f-1e-6f);
  const float cut = __expf(1.f - 1.f/(1.f - t*t));   // live => r<6, d!=s
  float base = 0.57735026918962576f * inv * cut;     // sqrt(2/RMAX)=sqrt(1/3)
  float* o = radY + (size_t)pos*16;
  const float pir = 0.52359877559829887f * r;        // pi*r/6
  float sT, cT;
  __sincosf(pir, &sT, &cT);
  const float twoc = 2.f*cT;
  float sp = 0.f, sc = sT;                           // sin(0), sin(theta)
  o[0] = base*sc;
  #pragma unroll
  for(int nb=2; nb<=8; ++nb){
    float sn = fmaf(twoc, sc, -sp);                  // Chebyshev sin recurrence
    o[nb-1] = base*sn;
    sp = sc; sc = sn;
  }
  o[8]  = 0.4886025119029199f*uy;                    // Y[1..8] (Y[0] folded)
  o[9]  = 0.4886025119029199f*uz;
  o[10] = 0.4886025119029199f*ux;
  o[11] = 1.0925484305920792f*ux*uy;
  o[12] = 1.0925484305920792f*uy*uz;
  o[13] = 0.31539156525252005f*(3.f*uz*uz-1.f);
  o[14] = 1.0925484305920792f*ux*uz;
  o[15] = 0.5462742152960396f*(ux*ux-uy*uy);
}

// ---------------------------------------------------------------------------
// Message passing, EDGE-MAJOR, fully-unrolled slot loop (R10/R14/R15 lineage).
// mp_phase = everything after staging (Wreg load, pipeline, flush).
// PS0 gathers from the L1-resident embed table via staged u8 Z (EMB=true).
// E (live count) now read from device memory; trailing blocks exit early and
// the tail-fallback path handles the one partial block per pass.
// ---------------------------------------------------------------------------
template<class PS>
__device__ __forceinline__ void mp_phase(
    int k0, int nE, const float* sRad, const int* sS, const unsigned char* sZb,
    const float* __restrict__ x_in, const float* __restrict__ emb,
    const float* __restrict__ W, float* __restrict__ ymsg, int f)
{
  constexpr int NP = PS::NP;
  constexpr int ALO = PS::ALO, AHI = PS::AHI, DA = AHI-ALO;
  constexpr int OD = PS::OD;
  constexpr int DEPTH = PS::DEPTH, NBUF = DEPTH+1;

  // path weights resident in VGPRs: lane f holds W[p][q][f].
  // l2==0 paths get Y0 pre-multiplied (Y[0] is a constant).
  float Wreg[NP][NBASIS];
  sfor<0,NP>([&](auto P){
    constexpr int p = P.value;
    constexpr bool fold = (PS::L[p][1]==0);
    sfor<0,NBASIS>([&](auto Q){
      float v = W[PS::WOFF + (p*NBASIS+Q.value)*N_FEAT + f];
      if constexpr (fold) v *= Y0C;
      Wreg[p][Q.value] = v;
    });
  });

  float msg[OD];
  sfor<0,OD>([&](auto C){ msg[C.value]=0.f; });

  auto gather = [&](float (&dst)[DA], int k){
    if constexpr (PS::EMB){
      const int zs = sZb[k];
      dst[0] = emb[zs*N_FEAT + f];       // 15KB table: L1-resident
    } else {
      const int s = sS[k] & 0xFFFF;
      const float* xb = x_in + (size_t)s*288 + ALO*N_FEAT + f;
      sfor<0,DA>([&](auto A){ dst[A.value] = xb[A.value*N_FEAT]; });
    }
  };

  auto compute = [&](const float (&xs)[DA], int k){
    const float* rp = sRad + k*16;
    const float4 q0 = *(const float4*)(rp);
    const float4 q1 = *(const float4*)(rp+4);
    const float4 q2 = *(const float4*)(rp+8);
    const float4 q3 = *(const float4*)(rp+12);
    const float rad[8] = {q0.x,q0.y,q0.z,q0.w,q1.x,q1.y,q1.z,q1.w};
    const float Yv[8]  = {q2.x,q2.y,q2.z,q2.w,q3.x,q3.y,q3.z,q3.w}; // Y[1..8]
    sfor<0,NP>([&](auto P){
      constexpr int p  = P.value;
      constexpr int l1 = PS::L[p][0], l2 = PS::L[p][1], l3 = PS::L[p][2];
      constexpr int o1 = LOFF[l1], o2 = LOFF[l2], o3 = LOFF[l3];
      float w = 0.f;
      sfor<0,NBASIS>([&](auto Q){ w = fmaf(rad[Q.value], Wreg[p][Q.value], w); });
      sfor<0,2*l2+1>([&](auto B){
        constexpr int b = B.value;
        float yw;
        if constexpr (l2==0) yw = w;            // Y0 folded into Wreg
        else                 yw = Yv[o2+b-1]*w; // Yv holds Y[1..8]
        sfor<0,2*l1+1>([&](auto A){
          constexpr int a = A.value;
          sfor<0,2*l3+1>([&](auto C){
            constexpr int c = C.value;
            constexpr float cgv = cgc::T.v[o1+a][o2+b][o3+c];
            if constexpr (cgv > 1e-7f || cgv < -1e-7f){
              msg[o3+c] = fmaf(cgv*xs[o1+a-ALO], yw, msg[o3+c]);
            }
          });
        });
      });
    });
  };

  auto flush = [&](int d){
    float* yb = ymsg + ((size_t)d*OD)*N_FEAT + f;
    sfor<0,OD>([&](auto C){
      atomicAdd(yb + C.value*N_FEAT, msg[C.value]);
      msg[C.value] = 0.f;
    });
  };

  if (k0 + SPAN <= nE){
    // -------- main path: exact SPAN edges, full unroll, register pipeline --
    float buf[NBUF][DA];
    sfor<0,DEPTH>([&](auto J){ gather(buf[J.value], k0 + J.value); });
    int vcur = sS[k0];
    sfor<0,SPAN>([&](auto I){
      constexpr int i = I.value;
      int vnext;
      if constexpr (i+1 < SPAN) vnext = sS[k0+i+1]; else vnext = -1;
      if constexpr (i+DEPTH < SPAN) gather(buf[(i+DEPTH)%NBUF], k0+i+DEPTH);
      compute(buf[i%NBUF], k0+i);
      if (i == SPAN-1 || (vnext>>16) != (vcur>>16)) flush(vcur>>16);
      vcur = vnext;
    });
  } else {
    // -------- tail fallback (partial block): simple 1-deep sequential ------
    const int k1 = (k0+SPAN < nE) ? k0+SPAN : nE;
    for (int k=k0; k<k1; ++k){
      float xs[DA];
      gather(xs, k);
      compute(xs, k);
      const int dc = sS[k]>>16;
      const int dn = (k+1 < k1) ? (sS[k+1]>>16) : -1;
      if (dn != dc) flush(dc);
    }
  }
}

// cooperative stage helper: radY burst + packed src/dst (+ optional u8 Z)
template<bool EMB>
__device__ __forceinline__ int mp_stage(
    int bid, float* sRad, int* sS, unsigned char* sZb,
    const int* __restrict__ srcsP, const unsigned char* __restrict__ zsrc,
    const float* __restrict__ radY, int E)
{
  const int tid  = threadIdx.x;
  const int base = bid * BEDGES;
  const int nE   = (base + BEDGES <= E) ? BEDGES : (E - base);
  {
    const float4* g4 = (const float4*)(radY + (size_t)base*16);
    float4* s4 = (float4*)sRad;
    const int n4 = nE*4;                    // nE*16/4 (loops skip if nE<=0)
    for (int i=tid; i<n4; i+=256) s4[i] = g4[i];
    for (int i=tid; i<nE;  i+=256) sS[i] = srcsP[base+i];
    if constexpr (EMB){
      for (int i=tid; i<nE; i+=256) sZb[i] = zsrc[base+i];
    }
  }
  __syncthreads();
  return nE;
}

template<class PS>
__global__ void __launch_bounds__(256, PS::MINW) mp_kernel(
    const int* __restrict__ srcsP, const unsigned char* __restrict__ zsrc,
    const float* __restrict__ radY, const float* __restrict__ x_in,
    const float* __restrict__ emb, const float* __restrict__ W,
    float* __restrict__ ymsg, const int* __restrict__ Elive)
{
  __shared__ float sRad[BEDGES*16];
  __shared__ int   sS[BEDGES];
  __shared__ unsigned char sZb[BEDGES];
  const int E = Elive[0];
  const int nE = mp_stage<PS::EMB>(blockIdx.x, sRad, sS, sZb, srcsP, zsrc, radY, E);
  const int f  = threadIdx.x & 31;
  const int k0 = (threadIdx.x>>5)*SPAN;
  if (k0 >= nE) return;
  mp_phase<PS>(k0, nE, sRad, sS, sZb, x_in, emb, W, ymsg, f);
}

// layer-1 fused dispatch (R15 grid split, proven): first gMP blocks run
// PS1a, next gMP run PS1b.  Separate register-allocation paths; atomic
// accumulation makes the interleaved execution order safe.
__global__ void __launch_bounds__(256, 3) mp1_kernel(
    const int* __restrict__ srcsP, const float* __restrict__ radY,
    const float* __restrict__ x_in, const float* __restrict__ W,
    float* __restrict__ ymsg, const int* __restrict__ Elive, int gMP)
{
  __shared__ float sRad[BEDGES*16];
  __shared__ int   sS[BEDGES];
  const int E = Elive[0];
  const int b = blockIdx.x;
  if (b < gMP){
    const int nE = mp_stage<false>(b, sRad, sS, nullptr, srcsP, nullptr, radY, E);
    const int f  = threadIdx.x & 31;
    const int k0 = (threadIdx.x>>5)*SPAN;
    if (k0 >= nE) return;
    mp_phase<PS1a>(k0, nE, sRad, sS, nullptr, x_in, nullptr, W, ymsg, f);
  } else {
    const int nE = mp_stage<false>(b-gMP, sRad, sS, nullptr, srcsP, nullptr, radY, E);
    const int f  = threadIdx.x & 31;
    const int k0 = (threadIdx.x>>5)*SPAN;
    if (k0 >= nE) return;
    mp_phase<PS1b>(k0, nE, sRad, sS, nullptr, x_in, nullptr, W, ymsg, f);
  }
}

// ---------------------------------------------------------------------------
// Node update for iterations 0/1.  ZERO=true (iteration 0) additionally
// re-zeroes ymsg in place (race-free: each thread zeroes exactly the words
// it read) and zeroes ymsg2 for the final layer -> no hipMemsetAsync at all.
// ---------------------------------------------------------------------------
template<int DX, bool ZERO>
__global__ void __launch_bounds__(256) nodeA_kernel(
    const float* __restrict__ xin, float* __restrict__ ymsg,
    float* __restrict__ ymsg2,
    const float* __restrict__ K1, const float* __restrict__ b1,
    const float* __restrict__ K2, const float* __restrict__ b2,
    float* __restrict__ xout, int nN)
{
  __shared__ float sK1[1024], sK2[1024], sb1[32], sb2[32];
  __shared__ float tb[8][9][32];
  const int tid = threadIdx.x;
  for(int i=tid;i<1024;i+=256){ sK1[i]=K1[i]; sK2[i]=K2[i]; }
  if(tid<32){ sb1[tid]=b1[tid]; sb2[tid]=b2[tid]; }
  __syncthreads();
  const int h = tid>>5, f = tid&31;
  const int n = blockIdx.x*8 + h;
  const bool valid = n < nN;
  const int nc = valid ? n : 0;
  float xi[9];
  #pragma unroll
  for(int c=0;c<9;++c){
    float t = ymsg[((size_t)nc*9+c)*32+f];
    if (ZERO && valid) ymsg[((size_t)nc*9+c)*32+f] = 0.f;
    float x = 0.f;
    if (c<DX) x = xin[((size_t)nc*9+c)*32+f];
    xi[c]=x;
    tb[h][c][f] = t + x;
  }
  if (ZERO && valid) ymsg2[(size_t)nc*32+f] = 0.f;
  __syncthreads();
  float u[9];
  #pragma unroll
  for(int c=0;c<9;++c){
    float acc = (c==0) ? sb1[f] : 0.f;
    #pragma unroll
    for(int g=0;g<32;++g) acc = fmaf(tb[h][c][g], sK1[g*32+f], acc);
    u[c]=acc;
  }
  const float gate = 1.f/(1.f+expf(-u[0]));   // silu(s)=s*gate; others *gate
  __syncthreads();
  #pragma unroll
  for(int c=0;c<9;++c) tb[h][c][f] = u[c]*gate;
  __syncthreads();
  #pragma unroll
  for(int c=0;c<9;++c){
    float acc = (c==0) ? sb2[f] : 0.f;
    #pragma unroll
    for(int g=0;g<32;++g) acc = fmaf(tb[h][c][g], sK2[g*32+f], acc);
    if (valid) xout[((size_t)n*9+c)*32+f] = acc + ((c<DX) ? xi[c] : 0.f);
  }
}

// Final iteration node update: scalar channel only; writes d_out (nN,32)
__global__ void __launch_bounds__(256) nodeB_kernel(
    const float* __restrict__ xin, const float* __restrict__ msg0,
    const float* __restrict__ K1, const float* __restrict__ b1,
    const float* __restrict__ K2, const float* __restrict__ b2,
    float* __restrict__ out, int nN)
{
  __shared__ float sK1[1024], sK2[1024], sb1[32], sb2[32];
  __shared__ float tb[8][32];
  const int tid = threadIdx.x;
  for(int i=tid;i<1024;i+=256){ sK1[i]=K1[i]; sK2[i]=K2[i]; }
  if(tid<32){ sb1[tid]=b1[tid]; sb2[tid]=b2[tid]; }
  __syncthreads();
  const int h = tid>>5, f = tid&31;
  const int n = blockIdx.x*8 + h;
  const bool valid = n < nN;
  const int nc = valid ? n : 0;
  const float x0 = xin[(size_t)nc*288 + f];      // x[:, 0:1] scalar channel
  tb[h][f] = msg0[(size_t)nc*32+f] + x0;
  __syncthreads();
  float acc = sb1[f];
  #pragma unroll
  for(int g=0;g<32;++g) acc = fmaf(tb[h][g], sK1[g*32+f], acc);
  const float gate = 1.f/(1.f+expf(-acc));
  const float v = acc*gate;
  __syncthreads();
  tb[h][f] = v;
  __syncthreads();
  float acc2 = sb2[f];
  #pragma unroll
  for(int g=0;g<32;++g) acc2 = fmaf(tb[h][g], sK2[g*32+f], acc2);
  if (valid) out[(size_t)n*32+f] = x0 + acc2;
}

// ---------------------------------------------------------------------------
extern "C" void kernel_launch(void* const* d_in, const int* in_sizes, int n_in,
                              void* d_out, int out_size, void* d_ws, size_t ws_size,
                              hipStream_t stream) {
  const float* dr    = (const float*)d_in[0];
  const int*   Z     = (const int*)  d_in[1];
  const int*   nbr   = (const int*)  d_in[2];
  const float* embed = (const float*)d_in[3];
  const float* wmp0  = (const float*)d_in[4];
  const float* wmp1  = (const float*)d_in[5];
  const float* wmp2  = (const float*)d_in[6];
  const float* dk1   = (const float*)d_in[7];
  const float* db1   = (const float*)d_in[8];
  const float* dk2   = (const float*)d_in[9];
  const float* db2   = (const float*)d_in[10];
  const int nN = in_sizes[1];
  const int E  = in_sizes[2]/2;
  const int* idx_i = nbr;       // dst
  const int* idx_j = nbr + E;   // src

  // workspace carve-up (256B aligned)
  uintptr_t base = (uintptr_t)d_ws;
  auto alloc = [&](size_t bytes)->void*{
    uintptr_t p = (base + 255) & ~(uintptr_t)255;
    base = p + bytes;
    return (void*)p;
  };
  float* radY    = (float*)alloc((size_t)E*16*4);
  int*   cnt     = (int*)  alloc((size_t)nN*4);
  int*   cursor  = (int*)  alloc((size_t)nN*4);
  int*   Elive   = (int*)  alloc(256);
  int*   srcsP   = (int*)  alloc((size_t)E*4);
  unsigned char* zsrc = (unsigned char*)alloc((size_t)E);
  float* xA      = (float*)alloc((size_t)nN*288*4);
  float* xB      = (float*)alloc((size_t)nN*288*4);
  float* ymsg    = (float*)alloc((size_t)nN*288*4);
  float* ymsg2   = (float*)alloc((size_t)nN*32*4);

  const int gE  = (E+255)/256;
  const int gI  = (nN*N_FEAT+255)/256;
  const int gND = (nN+7)/8;                       // 8 nodes (half-waves) per block
  const int gMP = (E + BEDGES - 1) / BEDGES;      // sized for full E; trailing
                                                  // blocks exit early on Elive

  // prologue: init fuses cnt-zero + embedding + ymsg-zero; count filters
  // dead edges (r>=6 or self-loop: provably zero contribution); fill+geom
  // emits CSR records for live edges only.
  init_kernel    <<<gI, 256, 0, stream>>>(embed, Z, xA, ymsg, cnt, nN);
  count_kernel   <<<gE, 256, 0, stream>>>(idx_i, idx_j, dr, cnt, E);
  scan_kernel    <<<1, 1024, 0, stream>>>(cnt, cursor, Elive, nN);
  fillgeom_kernel<<<gE, 256, 0, stream>>>(idx_i, idx_j, Z, dr, cursor, srcsP, zsrc, radY, E);

  // iteration 0 (ymsg pre-zeroed by init; PS0 gathers embed directly)
  mp_kernel<PS0><<<gMP, 256, 0, stream>>>(srcsP, zsrc, radY, xA, embed, wmp0, ymsg, Elive);
  nodeA_kernel<1,true><<<gND, 256, 0, stream>>>(xA, ymsg, ymsg2, dk1, db1, dk2, db2, xB, nN);
  // iteration 1: PS1a+PS1b in ONE dispatch via grid split (ymsg re-zeroed
  // by nodeA<1,true> above)
  mp1_kernel<<<2*gMP, 256, 0, stream>>>(srcsP, radY, xB, wmp1, ymsg, Elive, gMP);
  nodeA_kernel<9,false><<<gND, 256, 0, stream>>>(xB, ymsg, ymsg2, dk1+1024, db1+32, dk2+1024, db2+32, xA, nN);
  // iteration 2 (scalar output into ymsg2, zeroed by nodeA<1,true>)
  mp_kernel<PS2><<<gMP, 256, 0, stream>>>(srcsP, zsrc, radY, xA, embed, wmp2, ymsg2, Elive);
  nodeB_kernel<<<gND, 256, 0, stream>>>(xA, ymsg2, dk1+2048, db1+64, dk2+2048, db2+64,
                                        (float*)d_out, nN);
}